// Round 3
// baseline (239.892 us; speedup 1.0000x reference)
//
#include <hip/hip_runtime.h>
#include <hip/hip_bf16.h>
#include <stdint.h>

typedef __bf16 v8bf __attribute__((ext_vector_type(8)));
typedef float  v4f  __attribute__((ext_vector_type(4)));
typedef unsigned short u16;

#define NTOK 16384
#define KDIM 1024

__device__ __forceinline__ u16 f2bf(float f) {
  uint32_t b = __builtin_bit_cast(uint32_t, f);
  b += 0x7FFFu + ((b >> 16) & 1u);
  return (u16)(b >> 16);
}

__device__ __forceinline__ void gl_lds16(const u16* g, u16* l) {
  __builtin_amdgcn_global_load_lds(
      (const __attribute__((address_space(1))) uint32_t*)g,
      (__attribute__((address_space(3))) uint32_t*)l,
      16, 0, 0);
}

// barriers/waits with sched fences (rule 18: compiler hoists past bare asm waits)
__device__ __forceinline__ void bar() {
  __builtin_amdgcn_sched_barrier(0);
  __builtin_amdgcn_s_barrier();
  __builtin_amdgcn_sched_barrier(0);
}
#define LGKM0() do { asm volatile("s_waitcnt lgkmcnt(0)" ::: "memory"); \
                     __builtin_amdgcn_sched_barrier(0); } while (0)
#define VMW(n)  do { asm volatile("s_waitcnt vmcnt(" #n ")" ::: "memory"); \
                     __builtin_amdgcn_sched_barrier(0); } while (0)

// ---------------- fp32 -> bf16 convert (8 elems/thread) ----------------
__global__ void cvt_bf16(const float* __restrict__ in, u16* __restrict__ out) {
  size_t i = ((size_t)blockIdx.x * 256 + threadIdx.x) * 8;
  float4 a = *(const float4*)(in + i);
  float4 b = *(const float4*)(in + i + 4);
  union { u16 u[8]; uint4 v; } pk;
  pk.u[0]=f2bf(a.x); pk.u[1]=f2bf(a.y); pk.u[2]=f2bf(a.z); pk.u[3]=f2bf(a.w);
  pk.u[4]=f2bf(b.x); pk.u[5]=f2bf(b.y); pk.u[6]=f2bf(b.z); pk.u[7]=f2bf(b.w);
  *(uint4*)(out + i) = pk.v;
}

// ---------------- C = A * B^T + bias ; 256x256 tile, BK=32 -------------
// 8 waves (2M x 4N), 4-phase pipelined K-loop, counted vmcnt (T3+T4),
// setprio (T5), XCD block swizzle (T1), LDS XOR-swizzle (T2).
//
// T2 swizzle: LDS row = 4 chunks of 16B. Chunk c of row r lives at slot
// c ^ (r&3) ^ ((r>>2)&3). 16 consecutive rows at fixed c then cover all 8
// 16B slot positions exactly twice -> 2-way = free (vs 8-way unswizzled).
// global_load_lds dest stays LINEAR (rule 21); the SOURCE global address
// carries the inverse permutation; frag reads apply it on the read side.
// For frag rows (lane&15 + 16f + 64*const) it folds to a per-lane constant.
template<int NTOT, bool OUT_BF16>
__global__ __launch_bounds__(512, 2)
void gemm_bt(const u16* __restrict__ A, const u16* __restrict__ Bw,
             const float* __restrict__ bias, void* __restrict__ out) {
  constexpr int NM = NTOK / 256;         // 64
  constexpr int NN = NTOT / 256;
  constexpr int NWG = NM * NN;           // %8 == 0 for both GEMMs
  constexpr int NT = KDIM / 32;          // 32 K-tiles
  const int bid = blockIdx.x;
  const int swz = (bid & 7) * (NWG / 8) + (bid >> 3);   // bijective XCD swizzle
  const int bm = swz % NM, bn = swz / NM;

  __shared__ __align__(16) u16 lds[2][2][256 * 32];     // 64 KiB

  const int tid = threadIdx.x, lane = tid & 63, w = tid >> 6;
  const int wr = w >> 2, wc = w & 3;

  v4f acc[8][4];
#pragma unroll
  for (int i = 0; i < 8; ++i)
#pragma unroll
    for (int j = 0; j < 4; ++j) acc[i][j] = v4f{0.f, 0.f, 0.f, 0.f};

  const u16* Ab = A  + (size_t)bm * 256 * KDIM;
  const u16* Bb = Bw + (size_t)bn * 256 * KDIM;

  // stage: one 16B chunk per thread per half (128 rows x 32 elems = 8KB).
  // LDS dest linear (tid*16B); source chunk pre-swizzled (inverse = same XOR).
  const size_t soff = (size_t)(tid >> 2) * KDIM
      + (size_t)((((tid & 3) ^ ((tid >> 2) & 3) ^ ((tid >> 4) & 3)) & 3) * 8);
  auto stage = [&](u16* dst, const u16* src) { gl_lds16(src + soff, dst + tid * 8); };

  // frag read offsets (elems); swizzled chunk index folds to per-lane const
  const int cks = ((lane >> 4) ^ (lane & 3) ^ ((lane >> 2) & 3)) & 3;
  const int aoff = (wr * 128 + (lane & 15)) * 32 + cks * 8;
  const int boff = (wc * 64  + (lane & 15)) * 32 + cks * 8;

#define QUAD(MF0, NF0) do {                                              \
  _Pragma("unroll") for (int qi = 0; qi < 4; ++qi)                       \
  _Pragma("unroll") for (int qj = 0; qj < 2; ++qj)                       \
    acc[(MF0)+qi][(NF0)+qj] = __builtin_amdgcn_mfma_f32_16x16x32_bf16(   \
        af[(MF0)+qi], bfr[(NF0)+qj], acc[(MF0)+qi][(NF0)+qj], 0, 0, 0);  \
} while (0)

  // prologue: tile0 (all 4 halves) + A halves of tile1
  stage(&lds[0][0][0], Ab);
  stage(&lds[0][0][4096], Ab + 128 * KDIM);
  stage(&lds[0][1][0], Bb);
  stage(&lds[0][1][4096], Bb + 128 * KDIM);
  stage(&lds[1][0][0], Ab + 32);
  stage(&lds[1][0][4096], Ab + 128 * KDIM + 32);
  VMW(2);
  bar();

  for (int t = 0; t < NT; ++t) {
    const int p = t & 1;
    const u16* La = lds[p][0];
    const u16* Lb = lds[p][1];
    u16* Sb = lds[p ^ 1][1];                 // B dest for tile t+1
    u16* Sa = lds[p][0];                     // A dest for tile t+2
    const u16* Bs = Bb + (size_t)(t + 1) * 32;
    const u16* As = Ab + (size_t)(t + 2) * 32;
    v8bf af[8], bfr[4];

    // ---- P0: read A0,B0 ; stage B-lo(t+1) ; compute Q(0,0)
#pragma unroll
    for (int f = 0; f < 4; ++f) af[f] = *(const v8bf*)(La + aoff + f * 512);
#pragma unroll
    for (int f = 0; f < 2; ++f) bfr[f] = *(const v8bf*)(Lb + boff + f * 512);
    if (t + 1 < NT) stage(Sb, Bs);
    bar(); LGKM0();
    __builtin_amdgcn_s_setprio(1); QUAD(0, 0); __builtin_amdgcn_s_setprio(0);
    bar();

    // ---- P1: read A1,B1 ; stage B-hi(t+1) ; compute Q(4,2)
#pragma unroll
    for (int f = 4; f < 8; ++f) af[f] = *(const v8bf*)(La + aoff + f * 512);
#pragma unroll
    for (int f = 2; f < 4; ++f) bfr[f] = *(const v8bf*)(Lb + boff + f * 512);
    if (t + 1 < NT) stage(Sb + 4096, Bs + 128 * KDIM);
    bar(); LGKM0();
    __builtin_amdgcn_s_setprio(1); QUAD(4, 2); __builtin_amdgcn_s_setprio(0);
    bar();

    // ---- P2: stage A-lo(t+2) ; compute Q(0,2)
    if (t + 2 < NT) stage(Sa, As);
    bar();
    __builtin_amdgcn_s_setprio(1); QUAD(0, 2); __builtin_amdgcn_s_setprio(0);
    bar();

    // ---- P3: stage A-hi(t+2) ; compute Q(4,0) ; boundary wait
    if (t + 2 < NT) stage(Sa + 4096, As + 128 * KDIM);
    bar();
    __builtin_amdgcn_s_setprio(1); QUAD(4, 0); __builtin_amdgcn_s_setprio(0);
    if (t + 2 < NT) { VMW(2); } else { VMW(0); }
    bar();
  }
#undef QUAD

  // C/D layout: col = lane&15, row = (lane>>4)*4 + j
  const int col0 = bn * 256 + wc * 64 + (lane & 15);
  const int row0 = bm * 256 + wr * 128 + ((lane >> 4) << 2);
#pragma unroll
  for (int mf = 0; mf < 8; ++mf) {
#pragma unroll
    for (int nf = 0; nf < 4; ++nf) {
      const int gc = col0 + nf * 16;
      const float bv = bias[gc];
#pragma unroll
      for (int j = 0; j < 4; ++j) {
        const size_t idx = (size_t)(row0 + mf * 16 + j) * NTOT + gc;
        const float v = acc[mf][nf][j] + bv;
        if constexpr (OUT_BF16) ((u16*)out)[idx] = f2bf(v);
        else                    ((float*)out)[idx] = v;
      }
    }
  }
}

// ---------------- per-token head-mix attention -------------------------
__global__ __launch_bounds__(256)
void attn_mix(const u16* __restrict__ qkv, u16* __restrict__ outp) {
  __shared__ __align__(16) u16 sq[4][3072];
  __shared__ float sp[4][16][16];
  const int tid = threadIdx.x, lane = tid & 63, w = tid >> 6;
  const size_t tok = (size_t)blockIdx.x * 4 + w;
  const u16* src = qkv + tok * 3072;
#pragma unroll
  for (int i = 0; i < 6; ++i) {
    int t = i * 64 + lane;
    int row = t >> 3;
    int c = (t & 7) ^ (row & 7);
    gl_lds16(src + row * 64 + c * 8, &sq[w][t * 8]);
  }
  __syncthreads();

  const int h = lane >> 2, gb = lane & 3;
  v8bf qv[8];
#pragma unroll
  for (int c = 0; c < 8; ++c)
    qv[c] = *(const v8bf*)&sq[w][h * 64 + ((c ^ (h & 7)) * 8)];

  float s[4];
#pragma unroll
  for (int g4 = 0; g4 < 4; ++g4) {
    const int g = gb * 4 + g4;
    float a = 0.f;
#pragma unroll
    for (int c = 0; c < 8; ++c) {
      v8bf kv = *(const v8bf*)&sq[w][1024 + g * 64 + ((c ^ (g & 7)) * 8)];
#pragma unroll
      for (int j = 0; j < 8; ++j) a += (float)qv[c][j] * (float)kv[j];
    }
    s[g4] = a * 0.125f;
  }
  float m = fmaxf(fmaxf(s[0], s[1]), fmaxf(s[2], s[3]));
  m = fmaxf(m, __shfl_xor(m, 1));
  m = fmaxf(m, __shfl_xor(m, 2));
  float p[4], sum = 0.f;
#pragma unroll
  for (int g4 = 0; g4 < 4; ++g4) { p[g4] = __expf(s[g4] - m); sum += p[g4]; }
  sum += __shfl_xor(sum, 1);
  sum += __shfl_xor(sum, 2);
  const float inv = 1.f / sum;
#pragma unroll
  for (int g4 = 0; g4 < 4; ++g4) sp[w][h][gb * 4 + g4] = p[g4] * inv;
  __syncthreads();

  float o[16];
#pragma unroll
  for (int j = 0; j < 16; ++j) o[j] = 0.f;
  const int db = gb;
#pragma unroll
  for (int g = 0; g < 16; ++g) {
    const float a = sp[w][h][g];
    v8bf v0 = *(const v8bf*)&sq[w][2048 + g * 64 + (((db * 2)     ^ (g & 7)) * 8)];
    v8bf v1 = *(const v8bf*)&sq[w][2048 + g * 64 + (((db * 2 + 1) ^ (g & 7)) * 8)];
#pragma unroll
    for (int j = 0; j < 8; ++j) { o[j] += a * (float)v0[j]; o[8 + j] += a * (float)v1[j]; }
  }
  union { u16 u[16]; uint4 v[2]; } ob;
#pragma unroll
  for (int j = 0; j < 16; ++j) ob.u[j] = f2bf(o[j]);
  u16* dst = outp + tok * 1024 + h * 64 + db * 16;
  *(uint4*)dst = ob.v[0];
  *((uint4*)dst + 1) = ob.v[1];
}

extern "C" void kernel_launch(void* const* d_in, const int* in_sizes, int n_in,
                              void* d_out, int out_size, void* d_ws, size_t ws_size,
                              hipStream_t stream) {
  const float* x      = (const float*)d_in[0];
  const float* w_qkv  = (const float*)d_in[1];
  const float* b_qkv  = (const float*)d_in[2];
  const float* w_proj = (const float*)d_in[3];
  const float* b_proj = (const float*)d_in[4];

  char* ws = (char*)d_ws;
  u16* x_bf    = (u16*)(ws);
  u16* wqkv_bf = (u16*)(ws + (size_t)33554432);
  u16* wp_bf   = (u16*)(ws + (size_t)39845888);
  u16* qkv_bf  = (u16*)(ws + (size_t)41943040);
  u16* at_bf   = (u16*)(ws + (size_t)142606336);

  cvt_bf16<<<dim3(8192), dim3(256), 0, stream>>>(x, x_bf);
  cvt_bf16<<<dim3(1536), dim3(256), 0, stream>>>(w_qkv, wqkv_bf);
  cvt_bf16<<<dim3(512),  dim3(256), 0, stream>>>(w_proj, wp_bf);

  gemm_bt<3072, true ><<<dim3(768), dim3(512), 0, stream>>>(x_bf, wqkv_bf, b_qkv, qkv_bf);
  attn_mix<<<dim3(4096), dim3(256), 0, stream>>>(qkv_bf, at_bf);
  gemm_bt<1024, false><<<dim3(256), dim3(512), 0, stream>>>(at_bf, wp_bf, b_proj, d_out);
}

// Round 4
// 221.867 us; speedup vs baseline: 1.0812x; 1.0812x over previous
//
#include <hip/hip_runtime.h>
#include <hip/hip_bf16.h>
#include <stdint.h>

typedef __bf16 v8bf __attribute__((ext_vector_type(8)));
typedef float  v4f  __attribute__((ext_vector_type(4)));
typedef unsigned short u16;

#define NTOK 16384
#define KDIM 1024

__device__ __forceinline__ u16 f2bf(float f) {
  uint32_t b = __builtin_bit_cast(uint32_t, f);
  b += 0x7FFFu + ((b >> 16) & 1u);
  return (u16)(b >> 16);
}

__device__ __forceinline__ void gl_lds16(const u16* g, u16* l) {
  __builtin_amdgcn_global_load_lds(
      (const __attribute__((address_space(1))) uint32_t*)g,
      (__attribute__((address_space(3))) uint32_t*)l,
      16, 0, 0);
}

__device__ __forceinline__ void bar() {
  __builtin_amdgcn_sched_barrier(0);
  __builtin_amdgcn_s_barrier();
  __builtin_amdgcn_sched_barrier(0);
}
#define LGKM0() do { asm volatile("s_waitcnt lgkmcnt(0)" ::: "memory"); \
                     __builtin_amdgcn_sched_barrier(0); } while (0)
#define VMW(n)  do { asm volatile("s_waitcnt vmcnt(" #n ")" ::: "memory"); \
                     __builtin_amdgcn_sched_barrier(0); } while (0)

// ---------------- fused fp32 -> bf16 convert for all three tensors -----
__global__ void cvt_all(const float* __restrict__ x, const float* __restrict__ wq,
                        const float* __restrict__ wp, u16* __restrict__ xo,
                        u16* __restrict__ wqo, u16* __restrict__ wpo) {
  size_t id = (size_t)blockIdx.x * 256 + threadIdx.x;
  const float* src; u16* dst;
  if (id < 2097152)      { src = x  + id * 8;              dst = xo  + id * 8; }
  else if (id < 2490368) { src = wq + (id - 2097152) * 8;  dst = wqo + (id - 2097152) * 8; }
  else                   { src = wp + (id - 2490368) * 8;  dst = wpo + (id - 2490368) * 8; }
  float4 a = *(const float4*)(src);
  float4 b = *(const float4*)(src + 4);
  union { u16 u[8]; uint4 v; } pk;
  pk.u[0]=f2bf(a.x); pk.u[1]=f2bf(a.y); pk.u[2]=f2bf(a.z); pk.u[3]=f2bf(a.w);
  pk.u[4]=f2bf(b.x); pk.u[5]=f2bf(b.y); pk.u[6]=f2bf(b.z); pk.u[7]=f2bf(b.w);
  *(uint4*)(dst) = pk.v;
}

// ---------------- C = A * B^T + bias ; 256x256 tile, BK=32 -------------
// v4 schedule: 4 phases per TWO K-tiles (t0=2j -> buf0, t1=2j+1 -> buf1).
// Each phase: {ds_read frags ; issue 2 global_load_lds ; bar ; lgkmcnt(0) ;
// setprio(1) 16 MFMA setprio(0) ; [counted vmcnt] ; bar}.
//
// Staging ledger (2 loads per tile-half A or B, issue order left->right):
//   P0: stage A(t1)   -> buf1.A   (old A(t1-2) last read prev-iter P3, fenced by its bar2)
//   P1: stage B(t0+2) -> buf0.B   (B(t0) consumed into regs at P0's lgkm0)
//   P2: stage A(t0+2) -> buf0.A   (A(t0) consumed by P1's lgkm0)
//   P3: stage B(t1+2) -> buf1.B   (B(t1) consumed by P2's lgkm0)
// Waits: end-P1 in-flight = [B(t1),A(t1),B(t0+2)] -> VMW(2) lands t1 for P2.
//        end-P3 in-flight = [B(t0+2),A(t0+2),B(t1+2)] -> VMW(2) lands t0+2 for next P0.
// Tail (last iter): B-stage skipped -> VMW(0) drains the 4 remaining.
// Barriers: 4 per K-tile (was 8); in-flight depth 6; MFMA clusters of 16.
template<int NTOT, bool OUT_BF16>
__global__ __launch_bounds__(512, 2)
void gemm_bt(const u16* __restrict__ A, const u16* __restrict__ Bw,
             const float* __restrict__ bias, void* __restrict__ out) {
  constexpr int NM = NTOK / 256;
  constexpr int NN = NTOT / 256;
  constexpr int NWG = NM * NN;           // %8 == 0 for both GEMMs
  constexpr int NT = KDIM / 32;          // 32 K-tiles, 16 iterations
  const int bid = blockIdx.x;
  const int swz = (bid & 7) * (NWG / 8) + (bid >> 3);   // bijective XCD swizzle
  const int bm = swz % NM, bn = swz / NM;

  __shared__ __align__(16) u16 lds[2][2][256 * 32];     // [buf][A|B], 64 KiB

  const int tid = threadIdx.x, lane = tid & 63, w = tid >> 6;
  const int wr = w >> 2, wc = w & 3;

  v4f acc[8][4];
#pragma unroll
  for (int i = 0; i < 8; ++i)
#pragma unroll
    for (int j = 0; j < 4; ++j) acc[i][j] = v4f{0.f, 0.f, 0.f, 0.f};

  const u16* Ab = A  + (size_t)bm * 256 * KDIM;
  const u16* Bb = Bw + (size_t)bn * 256 * KDIM;

  // staging: thread covers chunks tid and tid+512 of a 256x32 tile (16KB).
  // LDS dest linear; global source carries the (free) chunk XOR permutation.
  const size_t soff0 = (size_t)(tid >> 2) * KDIM
      + (size_t)((((tid & 3) ^ ((tid >> 2) & 3) ^ ((tid >> 4) & 3)) & 3) * 8);
  auto stage2 = [&](u16* dst, const u16* src) {
    gl_lds16(src + soff0, dst + (size_t)tid * 8);
    gl_lds16(src + soff0 + (size_t)128 * KDIM, dst + (size_t)tid * 8 + 4096);
  };

  // frag reads: swizzled chunk folds to a per-lane constant (f-independent)
  const int cks = ((lane >> 4) ^ (lane & 3) ^ ((lane >> 2) & 3)) & 3;
  const int aoff = (wr * 128 + (lane & 15)) * 32 + cks * 8;
  const int boff = (wc * 64  + (lane & 15)) * 32 + cks * 8;

#define HALFSTEP(CUR, TA, TB) do {                                            \
  const u16* La_ = lds[CUR][0];                                               \
  const u16* Lb_ = lds[CUR][1];                                               \
  v8bf af[4], bf4[4];                                                         \
  _Pragma("unroll") for (int f = 0; f < 4; ++f)                               \
    af[f] = *(const v8bf*)(La_ + aoff + f * 512);                             \
  _Pragma("unroll") for (int f = 0; f < 4; ++f)                               \
    bf4[f] = *(const v8bf*)(Lb_ + boff + f * 512);                            \
  if ((TA) < NT) stage2(&lds[(CUR) ^ 1][0][0], Ab + (size_t)(TA) * 32);       \
  bar(); LGKM0();                                                             \
  __builtin_amdgcn_s_setprio(1);                                              \
  _Pragma("unroll") for (int qi = 0; qi < 4; ++qi)                            \
  _Pragma("unroll") for (int qj = 0; qj < 4; ++qj)                            \
    acc[qi][qj] = __builtin_amdgcn_mfma_f32_16x16x32_bf16(                    \
        af[qi], bf4[qj], acc[qi][qj], 0, 0, 0);                               \
  __builtin_amdgcn_s_setprio(0);                                              \
  bar();                                                                      \
  _Pragma("unroll") for (int f = 0; f < 4; ++f)                               \
    af[f] = *(const v8bf*)(La_ + aoff + (f + 4) * 512);                       \
  if ((TB) < NT) stage2(&lds[CUR][1][0], Bb + (size_t)(TB) * 32);             \
  bar(); LGKM0();                                                             \
  __builtin_amdgcn_s_setprio(1);                                              \
  _Pragma("unroll") for (int qi = 0; qi < 4; ++qi)                            \
  _Pragma("unroll") for (int qj = 0; qj < 4; ++qj)                            \
    acc[4 + qi][qj] = __builtin_amdgcn_mfma_f32_16x16x32_bf16(                \
        af[qi], bf4[qj], acc[4 + qi][qj], 0, 0, 0);                           \
  __builtin_amdgcn_s_setprio(0);                                              \
  if ((TB) < NT) { VMW(2); } else { VMW(0); }                                 \
  bar();                                                                      \
} while (0)

  // prologue: B(0), A(0), B(1); drain to B(1) in flight.
  stage2(&lds[0][1][0], Bb);
  stage2(&lds[0][0][0], Ab);
  stage2(&lds[1][1][0], Bb + 32);
  VMW(2);
  bar();

  for (int j = 0; j < NT / 2; ++j) {
    HALFSTEP(0, 2 * j + 1, 2 * j + 2);
    HALFSTEP(1, 2 * j + 2, 2 * j + 3);
  }
#undef HALFSTEP

  // C/D layout: col = lane&15, row = (lane>>4)*4 + j
  const int col0 = bn * 256 + wc * 64 + (lane & 15);
  const int row0 = bm * 256 + wr * 128 + ((lane >> 4) << 2);
#pragma unroll
  for (int mf = 0; mf < 8; ++mf) {
#pragma unroll
    for (int nf = 0; nf < 4; ++nf) {
      const int gc = col0 + nf * 16;
      const float bv = bias[gc];
#pragma unroll
      for (int j = 0; j < 4; ++j) {
        const size_t idx = (size_t)(row0 + mf * 16 + j) * NTOT + gc;
        const float v = acc[mf][nf][j] + bv;
        if constexpr (OUT_BF16) ((u16*)out)[idx] = f2bf(v);
        else                    ((float*)out)[idx] = v;
      }
    }
  }
}

// ---------------- per-token head-mix attention -------------------------
__global__ __launch_bounds__(256)
void attn_mix(const u16* __restrict__ qkv, u16* __restrict__ outp) {
  __shared__ __align__(16) u16 sq[4][3072];
  __shared__ float sp[4][16][16];
  const int tid = threadIdx.x, lane = tid & 63, w = tid >> 6;
  const size_t tok = (size_t)blockIdx.x * 4 + w;
  const u16* src = qkv + tok * 3072;
#pragma unroll
  for (int i = 0; i < 6; ++i) {
    int t = i * 64 + lane;
    int row = t >> 3;
    int c = (t & 7) ^ (row & 7);
    gl_lds16(src + row * 64 + c * 8, &sq[w][t * 8]);
  }
  __syncthreads();

  const int h = lane >> 2, gb = lane & 3;
  v8bf qv[8];
#pragma unroll
  for (int c = 0; c < 8; ++c)
    qv[c] = *(const v8bf*)&sq[w][h * 64 + ((c ^ (h & 7)) * 8)];

  float s[4];
#pragma unroll
  for (int g4 = 0; g4 < 4; ++g4) {
    const int g = gb * 4 + g4;
    float a = 0.f;
#pragma unroll
    for (int c = 0; c < 8; ++c) {
      v8bf kv = *(const v8bf*)&sq[w][1024 + g * 64 + ((c ^ (g & 7)) * 8)];
#pragma unroll
      for (int j = 0; j < 8; ++j) a += (float)qv[c][j] * (float)kv[j];
    }
    s[g4] = a * 0.125f;
  }
  float m = fmaxf(fmaxf(s[0], s[1]), fmaxf(s[2], s[3]));
  m = fmaxf(m, __shfl_xor(m, 1));
  m = fmaxf(m, __shfl_xor(m, 2));
  float p[4], sum = 0.f;
#pragma unroll
  for (int g4 = 0; g4 < 4; ++g4) { p[g4] = __expf(s[g4] - m); sum += p[g4]; }
  sum += __shfl_xor(sum, 1);
  sum += __shfl_xor(sum, 2);
  const float inv = 1.f / sum;
#pragma unroll
  for (int g4 = 0; g4 < 4; ++g4) sp[w][h][gb * 4 + g4] = p[g4] * inv;
  __syncthreads();

  float o[16];
#pragma unroll
  for (int j = 0; j < 16; ++j) o[j] = 0.f;
  const int db = gb;
#pragma unroll
  for (int g = 0; g < 16; ++g) {
    const float a = sp[w][h][g];
    v8bf v0 = *(const v8bf*)&sq[w][2048 + g * 64 + (((db * 2)     ^ (g & 7)) * 8)];
    v8bf v1 = *(const v8bf*)&sq[w][2048 + g * 64 + (((db * 2 + 1) ^ (g & 7)) * 8)];
#pragma unroll
    for (int j = 0; j < 8; ++j) { o[j] += a * (float)v0[j]; o[8 + j] += a * (float)v1[j]; }
  }
  union { u16 u[16]; uint4 v[2]; } ob;
#pragma unroll
  for (int j = 0; j < 16; ++j) ob.u[j] = f2bf(o[j]);
  u16* dst = outp + tok * 1024 + h * 64 + db * 16;
  *(uint4*)dst = ob.v[0];
  *((uint4*)dst + 1) = ob.v[1];
}

extern "C" void kernel_launch(void* const* d_in, const int* in_sizes, int n_in,
                              void* d_out, int out_size, void* d_ws, size_t ws_size,
                              hipStream_t stream) {
  const float* x      = (const float*)d_in[0];
  const float* w_qkv  = (const float*)d_in[1];
  const float* b_qkv  = (const float*)d_in[2];
  const float* w_proj = (const float*)d_in[3];
  const float* b_proj = (const float*)d_in[4];

  char* ws = (char*)d_ws;
  u16* x_bf    = (u16*)(ws);
  u16* wqkv_bf = (u16*)(ws + (size_t)33554432);
  u16* wp_bf   = (u16*)(ws + (size_t)39845888);
  u16* qkv_bf  = (u16*)(ws + (size_t)41943040);
  u16* at_bf   = (u16*)(ws + (size_t)142606336);

  cvt_all<<<dim3(10240), dim3(256), 0, stream>>>(x, w_qkv, w_proj,
                                                 x_bf, wqkv_bf, wp_bf);

  gemm_bt<3072, true ><<<dim3(768), dim3(512), 0, stream>>>(x_bf, wqkv_bf, b_qkv, qkv_bf);
  attn_mix<<<dim3(4096), dim3(256), 0, stream>>>(qkv_bf, at_bf);
  gemm_bt<1024, false><<<dim3(256), dim3(512), 0, stream>>>(at_bf, wp_bf, b_proj, d_out);
}